// Round 1
// baseline (218.996 us; speedup 1.0000x reference)
//
#include <hip/hip_runtime.h>
#include <stdint.h>

// Binde ESN: 28-step coupled tanh recurrence, B=32768, MID=128.
// One persistent kernel: block = 16 batch rows, 4 waves, state in LDS,
// weights as MFMA A-fragments in VGPRs, mfma_f32_16x16x32_bf16 everywhere.
// Transposed form X^T = W^T @ X^T so batch is the 16-wide B-operand dim.

typedef __attribute__((ext_vector_type(8))) short  short8;   // bf16x8 frag (4 VGPR)
typedef __attribute__((ext_vector_type(4))) float  float4v;  // f32 acc (4 VGPR)

#define SEQ 28

__device__ __forceinline__ unsigned short f2bf(float f) {
    uint32_t u = __builtin_bit_cast(uint32_t, f);
    u += 0x7fffu + ((u >> 16) & 1u);            // RNE
    return (unsigned short)(u >> 16);
}

__device__ __forceinline__ float fast_tanh(float x) {
    float e = __builtin_exp2f(x * 2.885390081777927f);   // e^{2x}
    return 1.0f - 2.0f * __builtin_amdgcn_rcpf(e + 1.0f);
}

__device__ __forceinline__ uint64_t pack4bf(float a, float b, float c, float d) {
    uint32_t lo = (uint32_t)f2bf(a) | ((uint32_t)f2bf(b) << 16);
    uint32_t hi = (uint32_t)f2bf(c) | ((uint32_t)f2bf(d) << 16);
    return (uint64_t)lo | ((uint64_t)hi << 32);
}

// ---------------- ws byte layout ----------------
// MATS  [0,      131072) : 4 mats * 4 kk * 8 nt * 64 lanes * 8 els, bf16
//                          frag(m,kk,nt): el = ((m*4+kk)*8+nt)*512 + l*8 + j
//                          value = M^T[fout=16nt+(l&15)][fin=32kk+8*(l>>4)+j]
// WIN   [131072, 139264) : 8 nt * 512 (k = fin 0..31, zero-padded >=28)
// FC    [139264, 143360) : 4 kk * 512 (rows fout 0..15, zero for >=10)
// B1    [143360, 143872) : f32[128]  b_in+b_x1+b_res21
// B2    [143872, 144384) : f32[128]  b_res12+b_x2
// FCB   [144384, 144448) : f32[16]   fc_b zero-padded

__global__ __launch_bounds__(256) void pack_kernel(
    const float* __restrict__ binde1, const float* __restrict__ binde2,
    const float* __restrict__ binde3, const float* __restrict__ binde4,
    const float* __restrict__ w_in,   const float* __restrict__ w_res1,
    const float* __restrict__ w_res12,const float* __restrict__ w_res2,
    const float* __restrict__ w_res21,const float* __restrict__ b_in,
    const float* __restrict__ b_x1,   const float* __restrict__ b_res12,
    const float* __restrict__ b_x2,   const float* __restrict__ b_res21,
    const float* __restrict__ fc_w,   const float* __restrict__ fc_b,
    char* __restrict__ ws)
{
    int i = blockIdx.x * 256 + threadIdx.x;
    unsigned short* bf = (unsigned short*)ws;
    if (i < 65536) {
        int el = i & 511, frag = i >> 9;
        int l = el >> 3, j = el & 7;
        int nt = frag & 7, mk = frag >> 3;
        int kk = mk & 3, m = mk >> 2;
        int fin  = 32*kk + 8*(l >> 4) + j;
        int fout = 16*nt + (l & 15);
        const float* W; const float* Msk;
        if      (m == 0) { W = w_res1;  Msk = binde1; }   // m1
        else if (m == 1) { W = w_res21; Msk = binde2; }   // m21
        else if (m == 2) { W = w_res12; Msk = binde3; }   // m12
        else             { W = w_res2;  Msk = binde4; }   // m2
        int idx = fin*128 + fout;
        bf[i] = f2bf(W[idx] * Msk[idx]);
    } else if (i < 69632) {                               // WIN
        int e = i - 65536;
        int el = e & 511, nt = e >> 9;
        int l = el >> 3, j = el & 7;
        int fin  = 8*(l >> 4) + j;
        int fout = 16*nt + (l & 15);
        float v = (fin < 28) ? w_in[fin*128 + fout] : 0.0f;
        bf[i] = f2bf(v);
    } else if (i < 71680) {                               // FC
        int e = i - 69632;
        int el = e & 511, kk = e >> 9;
        int l = el >> 3, j = el & 7;
        int fin = 32*kk + 8*(l >> 4) + j;
        int fo  = l & 15;
        float v = (fo < 10) ? fc_w[fin*10 + fo] : 0.0f;
        bf[i] = f2bf(v);
    } else if (i < 71808) {
        int f = i - 71680;
        ((float*)(ws + 143360))[f] = b_in[f] + b_x1[f] + b_res21[f];
    } else if (i < 71936) {
        int f = i - 71808;
        ((float*)(ws + 143872))[f] = b_res12[f] + b_x2[f];
    } else if (i < 71952) {
        int f = i - 71936;
        ((float*)(ws + 144384))[f] = (f < 10) ? fc_b[f] : 0.0f;
    }
}

// State LDS tiling: feat k, batch c -> el = (k>>3)*128 + c*8 + (k&7).
// Frag read (kk,h): short8 at (4*kk+h)*128 + c*8  -> k = 32kk+8h+j  (conflict-free b128)
// Epilogue write: feat = 16nt+4h+r -> base (2nt+(h>>1))*128 + c*8 + 4*(h&1), r contiguous (b64)

__global__ __launch_bounds__(256, 2) void esn_main(
    const float* __restrict__ x, const char* __restrict__ ws,
    float* __restrict__ out0, float* __restrict__ ox1, float* __restrict__ ox2)
{
    __shared__ __align__(16) unsigned short sX1[2048];  // tanh(x1_pre), bf16
    __shared__ __align__(16) unsigned short sP [2048];  // x1_pre, bf16
    __shared__ __align__(16) unsigned short sX2[2048];  // x2 (tanh'd), bf16

    const int tid = threadIdx.x;
    const int w = tid >> 6;          // wave 0..3 -> out-feature tiles {2w,2w+1}
    const int l = tid & 63;
    const int h = l >> 4;            // lanegroup 0..3
    const int c = l & 15;            // batch col 0..15
    const int b0 = blockIdx.x << 4;

    const unsigned short* mats = (const unsigned short*)ws;
    const unsigned short* winp = (const unsigned short*)(ws + 131072);
    const float* b1p = (const float*)(ws + 143360);
    const float* b2p = (const float*)(ws + 143872);

    // persistent weight fragments (~136 VGPR)
    short8 m1f[4][2], m21f[4][2], m12f[4][2], m2f[4][2], winf[2];
    float4v b1v[2], b2v[2];
#pragma unroll
    for (int ntl = 0; ntl < 2; ++ntl) {
        const int nt = 2*w + ntl;
        winf[ntl] = *(const short8*)&winp[nt*512 + l*8];
#pragma unroll
        for (int kk = 0; kk < 4; ++kk) {
            m1f [kk][ntl] = *(const short8*)&mats[((0*4+kk)*8 + nt)*512 + l*8];
            m21f[kk][ntl] = *(const short8*)&mats[((1*4+kk)*8 + nt)*512 + l*8];
            m12f[kk][ntl] = *(const short8*)&mats[((2*4+kk)*8 + nt)*512 + l*8];
            m2f [kk][ntl] = *(const short8*)&mats[((3*4+kk)*8 + nt)*512 + l*8];
        }
        b1v[ntl] = *(const float4v*)&b1p[16*nt + 4*h];
        b2v[ntl] = *(const float4v*)&b2p[16*nt + 4*h];
    }

    // zero initial state (x1 = x2 = 0)
    ((uint4*)sX1)[tid] = make_uint4(0u, 0u, 0u, 0u);
    ((uint4*)sX2)[tid] = make_uint4(0u, 0u, 0u, 0u);
    __syncthreads();

    const float* xrow = x + (size_t)(b0 + c) * 784 + 8*h;

#pragma unroll 1
    for (int ts = 0; ts < SEQ; ++ts) {
        // ---- Phase A: load state frags + xt frag ----
        short8 x1b[4], x2b[4];
#pragma unroll
        for (int kk = 0; kk < 4; ++kk) {
            const int a = (4*kk + h)*128 + c*8;
            x1b[kk] = *(const short8*)&sX1[a];
            x2b[kk] = *(const short8*)&sX2[a];
        }
        short8 xb;
        {
            const float* xp = xrow + ts*28;
            float4v xa = *(const float4v*)xp;
            float4v xc = {0.f, 0.f, 0.f, 0.f};
            if (h < 3) xc = *(const float4v*)(xp + 4);   // feat>=28 zero-padded
#pragma unroll
            for (int j = 0; j < 4; ++j) {
                xb[j]     = (short)f2bf(xa[j]);
                xb[4 + j] = (short)f2bf(xc[j]);
            }
        }
        __syncthreads();   // B1: all reads of sX1/sX2 done

        // ---- Phase B: x1_pre = Win^T xt + M1^T x1 + M21^T x2 + bias1 ----
        float4v acc1[2];
#pragma unroll
        for (int ntl = 0; ntl < 2; ++ntl) {
            float4v a = b1v[ntl];
            a = __builtin_amdgcn_mfma_f32_16x16x32_bf16(winf[ntl], xb, a, 0, 0, 0);
#pragma unroll
            for (int kk = 0; kk < 4; ++kk)
                a = __builtin_amdgcn_mfma_f32_16x16x32_bf16(m1f[kk][ntl], x1b[kk], a, 0, 0, 0);
#pragma unroll
            for (int kk = 0; kk < 4; ++kk)
                a = __builtin_amdgcn_mfma_f32_16x16x32_bf16(m21f[kk][ntl], x2b[kk], a, 0, 0, 0);
            acc1[ntl] = a;
        }
#pragma unroll
        for (int ntl = 0; ntl < 2; ++ntl) {
            const int nt = 2*w + ntl;
            const int ad = (2*nt + (h >> 1))*128 + c*8 + 4*(h & 1);
            float4v pre = acc1[ntl];
            float t0 = fast_tanh(pre[0]);
            float t1 = fast_tanh(pre[1]);
            float t2 = fast_tanh(pre[2]);
            float t3 = fast_tanh(pre[3]);
            *(uint64_t*)&sP [ad] = pack4bf(pre[0], pre[1], pre[2], pre[3]);
            *(uint64_t*)&sX1[ad] = pack4bf(t0, t1, t2, t3);
            if (ts == SEQ - 1) {                      // x1 output (f32, exact path)
                float4v o; o[0]=t0; o[1]=t1; o[2]=t2; o[3]=t3;
                *(float4v*)&ox1[(size_t)(b0 + c)*128 + 16*nt + 4*h] = o;
            }
        }
        __syncthreads();   // B2: sP/sX1 visible

        // ---- Phase C: x2 = tanh(M12^T x1_pre + M2^T x2 + bias2) ----
        short8 pb[4];
#pragma unroll
        for (int kk = 0; kk < 4; ++kk)
            pb[kk] = *(const short8*)&sP[(4*kk + h)*128 + c*8];
        float4v acc2[2];
#pragma unroll
        for (int ntl = 0; ntl < 2; ++ntl) {
            float4v a = b2v[ntl];
#pragma unroll
            for (int kk = 0; kk < 4; ++kk)
                a = __builtin_amdgcn_mfma_f32_16x16x32_bf16(m12f[kk][ntl], pb[kk], a, 0, 0, 0);
#pragma unroll
            for (int kk = 0; kk < 4; ++kk)
                a = __builtin_amdgcn_mfma_f32_16x16x32_bf16(m2f[kk][ntl], x2b[kk], a, 0, 0, 0);
            acc2[ntl] = a;
        }
#pragma unroll
        for (int ntl = 0; ntl < 2; ++ntl) {
            const int nt = 2*w + ntl;
            const int ad = (2*nt + (h >> 1))*128 + c*8 + 4*(h & 1);
            float t0 = fast_tanh(acc2[ntl][0]);
            float t1 = fast_tanh(acc2[ntl][1]);
            float t2 = fast_tanh(acc2[ntl][2]);
            float t3 = fast_tanh(acc2[ntl][3]);
            *(uint64_t*)&sX2[ad] = pack4bf(t0, t1, t2, t3);
            if (ts == SEQ - 1) {                      // x2 output (f32, exact path)
                float4v o; o[0]=t0; o[1]=t1; o[2]=t2; o[3]=t3;
                *(float4v*)&ox2[(size_t)(b0 + c)*128 + 16*nt + 4*h] = o;
            }
        }
        __syncthreads();   // B3: sX2 visible for next step's Phase A
    }

    // ---- head: out = fcW^T @ x2 + fc_b (one 16x16 tile per block) ----
    if (w == 0) {
        const unsigned short* fcp = (const unsigned short*)(ws + 139264);
        const float* fcb = (const float*)(ws + 144384);
        float4v a = {0.f, 0.f, 0.f, 0.f};
#pragma unroll
        for (int kk = 0; kk < 4; ++kk) {
            short8 fcf = *(const short8*)&fcp[kk*512 + l*8];
            short8 xf  = *(const short8*)&sX2[(4*kk + h)*128 + c*8];
            a = __builtin_amdgcn_mfma_f32_16x16x32_bf16(fcf, xf, a, 0, 0, 0);
        }
#pragma unroll
        for (int r = 0; r < 4; ++r) {
            const int fo = 4*h + r;
            if (fo < 10) out0[(size_t)(b0 + c)*10 + fo] = a[r] + fcb[fo];
        }
    }
}

extern "C" void kernel_launch(void* const* d_in, const int* in_sizes, int n_in,
                              void* d_out, int out_size, void* d_ws, size_t ws_size,
                              hipStream_t stream) {
    const float* x       = (const float*)d_in[0];
    const float* binde1  = (const float*)d_in[1];
    const float* binde2  = (const float*)d_in[2];
    const float* binde3  = (const float*)d_in[3];
    const float* binde4  = (const float*)d_in[4];
    const float* w_in    = (const float*)d_in[5];
    const float* w_res1  = (const float*)d_in[6];
    const float* w_res12 = (const float*)d_in[7];
    const float* w_res2  = (const float*)d_in[8];
    const float* w_res21 = (const float*)d_in[9];
    const float* b_in    = (const float*)d_in[10];
    const float* b_x1    = (const float*)d_in[11];
    const float* b_res12 = (const float*)d_in[12];
    const float* b_x2    = (const float*)d_in[13];
    const float* b_res21 = (const float*)d_in[14];
    const float* fc_w    = (const float*)d_in[15];
    const float* fc_b    = (const float*)d_in[16];

    const int B = in_sizes[0] / 784;
    float* out0 = (float*)d_out;
    float* ox1  = out0 + (size_t)B * 10;
    float* ox2  = ox1  + (size_t)B * 128;

    pack_kernel<<<282, 256, 0, stream>>>(binde1, binde2, binde3, binde4,
                                         w_in, w_res1, w_res12, w_res2, w_res21,
                                         b_in, b_x1, b_res12, b_x2, b_res21,
                                         fc_w, fc_b, (char*)d_ws);
    esn_main<<<B / 16, 256, 0, stream>>>(x, (const char*)d_ws, out0, ox1, ox2);
}